// Round 7
// baseline (308.222 us; speedup 1.0000x reference)
//
#include <hip/hip_runtime.h>
#include <hip/hip_bf16.h>

// EGCL, MFMA, 8-wave blocks for occupancy. B=8, N=256, NF=H=128.
// edge_input@ew1 factorized: T0[i] + T1[j] + dist*ew1[256] + adj*ew1[257].
// Per block (one (b,i)): 512 threads = 8 waves (wm 4 h-quarters x wn 2 j-halves),
// j-tiles of 64, 4 iters, 3 barriers/tile.
// GEMM1: mT[h][j] = sum_k ew2T[h][k]*h1[j][k]; GEMM2: c1T = cw1T * mT.
// Weights in VGPRs (64/thread, loaded once). B-fragments via swizzled LDS.

#define BB 8
#define NN 256
#define HD 128
#define JT 64
#define NT (NN/JT)

typedef short bf16x8 __attribute__((ext_vector_type(8)));
typedef float f32x4  __attribute__((ext_vector_type(4)));

__device__ __forceinline__ float sigmoidf_(float x){ return 1.0f/(1.0f+__expf(-x)); }
__device__ __forceinline__ float siluf_(float x){ return x/(1.0f+__expf(-x)); }
__device__ __forceinline__ unsigned int cvtpk_bf16(float lo, float hi){
    unsigned int r;
    asm("v_cvt_pk_bf16_f32 %0, %1, %2" : "=v"(r) : "v"(lo), "v"(hi));
    return r;
}
__device__ __forceinline__ unsigned short f2bf(float x){
    unsigned int u = __float_as_uint(x);
    u += 0x7FFF + ((u>>16)&1);
    return (unsigned short)(u>>16);
}
__device__ __forceinline__ float bf2f(unsigned short h){
    return __uint_as_float(((unsigned int)h)<<16);
}

#define MFMA_BF16(d,a,b) d = __builtin_amdgcn_mfma_f32_16x16x32_bf16(a, b, d, 0, 0, 0)

// ---------- prep kernels ----------

__global__ __launch_bounds__(128) void precompute_T(
    const float* __restrict__ nf, const float* __restrict__ ew1,
    unsigned short* __restrict__ T0, unsigned short* __restrict__ T1)
{
    __shared__ float nfs[HD];
    const int bi = blockIdx.x;
    const int h  = threadIdx.x;
    nfs[h] = nf[(size_t)bi*HD + h];
    __syncthreads();
    float a0 = 0.f, a1 = 0.f;
    #pragma unroll 4
    for (int f = 0; f < HD; ++f){
        const float v = nfs[f];
        a0 = fmaf(v, ew1[f*HD + h],      a0);
        a1 = fmaf(v, ew1[(HD+f)*HD + h], a1);
    }
    T0[bi*HD + h] = f2bf(a0);
    T1[bi*HD + h] = f2bf(a1);
}

// plain transposed bf16 weights: dst[m][h*128+k] = src_m[k][h]
__global__ __launch_bounds__(256) void prep_w(
    const float* __restrict__ ew2, const float* __restrict__ cw1,
    unsigned short* __restrict__ dst)
{
    const int e = blockIdx.x*256 + threadIdx.x;   // 0..32767
    const int m = e >> 14;
    const int rem = e & 16383;
    const int h = rem >> 7, k = rem & 127;
    const float* src = m ? cw1 : ew2;
    dst[e] = f2bf(src[k*HD + h]);
}

// ---------- main kernel ----------

__global__ __launch_bounds__(512, 4) void egcl_main(
    const float* __restrict__ nf,  const float* __restrict__ pos,
    const float* __restrict__ valid, const float* __restrict__ adj,
    const float* __restrict__ ew1,
    const float* __restrict__ cw2,
    const float* __restrict__ nw1, const float* __restrict__ nw2,
    const float* __restrict__ iw,
    const unsigned short* __restrict__ T0u, const unsigned short* __restrict__ T1u,
    const unsigned short* __restrict__ wE,  const unsigned short* __restrict__ wC,
    float* __restrict__ out)
{
    __shared__ unsigned short sH1[JT*HD];   // 16KB, [j][k] swizzled
    __shared__ unsigned short sM [JT*HD];   // 16KB, [j][h] swizzled
    __shared__ float gpart[4][JT];
    __shared__ float cpart[4][JT];
    __shared__ float msgp[2][HD];
    __shared__ float ni[2*HD], n1l[HD], np4[4][HD];
    __shared__ float red3[3];

    const int tid = threadIdx.x;
    const int bi  = blockIdx.x;
    const int b   = bi >> 8;
    const int w   = tid >> 6;          // wave 0..7
    const int wm  = w >> 1;            // h-quarter (32 h's)
    const int wn  = w & 1;             // j-half within 64-tile
    const int l   = tid & 63, lr = l & 15, lg = l >> 4;
    const int hp  = tid & 63,  jq = tid >> 6;   // P1 mapping: 8 j per thread
    const int hh  = tid & 127, q4 = tid >> 7;   // node-MLP mapping (4 K-quarters)

    // ---- load weight A-fragments into registers ONCE (rows h = wm*32+mt*16+lr) ----
    bf16x8 aE[2][4], aC[2][4];
    {
        const unsigned short* pE = wE + (((wm*32 + lr) << 7) + lg*8);
        const unsigned short* pC = wC + (((wm*32 + lr) << 7) + lg*8);
        #pragma unroll
        for (int mt = 0; mt < 2; ++mt)
            #pragma unroll
            for (int kk = 0; kk < 4; ++kk){
                aE[mt][kk] = *(const bf16x8*)(pE + (mt*16 << 7) + kk*32);
                aC[mt][kk] = *(const bf16x8*)(pC + (mt*16 << 7) + kk*32);
            }
    }

    // ---- per-thread P1 constants ----
    const float t0a = bf2f(T0u[bi*HD + 2*hp]);
    const float t0b = bf2f(T0u[bi*HD + 2*hp + 1]);
    const float w6a = ew1[256*HD + 2*hp], w6b = ew1[256*HD + 2*hp + 1];
    const float w7a = ew1[257*HD + 2*hp], w7b = ew1[257*HD + 2*hp + 1];
    const float pix = pos[bi*3+0], piy = pos[bi*3+1], piz = pos[bi*3+2];
    const float validi = valid[bi];
    const unsigned short* __restrict__ T1b = T1u + (size_t)(b*NN)*HD;
    const float* __restrict__ posb   = pos + (size_t)(b*NN)*3;
    const float* __restrict__ adjrow = adj + (size_t)bi*NN;

    float msgacc[8];
    #pragma unroll
    for (int s = 0; s < 8; ++s) msgacc[s] = 0.f;
    float pax = 0.f, pay = 0.f, paz = 0.f;   // tid<64 only

    for (int t = 0; t < NT; ++t){
        const int j0 = t*JT;

        // ---- P1: h1 = silu(first-layer preact) -> sH1 (bf16, swizzled) ----
        #pragma unroll
        for (int r = 0; r < 8; ++r){
            const int jl = jq*8 + r;
            const int j  = j0 + jl;
            const ushort2 t1v = *(const ushort2*)&T1b[(size_t)j*HD + 2*hp];
            const float pjx = posb[j*3+0], pjy = posb[j*3+1], pjz = posb[j*3+2];
            const float dx = pix-pjx, dy = piy-pjy, dz = piz-pjz;
            const float d2 = dx*dx + dy*dy + dz*dz;
            const float aj = adjrow[j];
            const float s0 = siluf_(fmaf(aj, w7a, fmaf(d2, w6a, t0a + bf2f(t1v.x))));
            const float s1 = siluf_(fmaf(aj, w7b, fmaf(d2, w6b, t0b + bf2f(t1v.y))));
            ((unsigned int*)sH1)[(jl*64 + hp) ^ ((jl&7)<<2)] = cvtpk_bf16(s0, s1);
        }
        __syncthreads();   // A: h1 ready

        // ---- GEMM1: m = silu(ew2T @ h1T) ----
        f32x4 acc[2][2];
        #pragma unroll
        for (int mt = 0; mt < 2; ++mt){
            acc[mt][0] = (f32x4){0.f,0.f,0.f,0.f};
            acc[mt][1] = (f32x4){0.f,0.f,0.f,0.f};
        }
        {
            const int jb0 = wn*32 + lr;
            const int jb1 = jb0 + 16;
            __builtin_amdgcn_s_setprio(1);
            #pragma unroll
            for (int kk = 0; kk < 4; ++kk){
                const int kb = kk*32 + lg*8;
                const bf16x8 b0 = *(const bf16x8*)&sH1[((jb0<<7) + kb) ^ ((jb0&7)<<3)];
                const bf16x8 b1 = *(const bf16x8*)&sH1[((jb1<<7) + kb) ^ ((jb1&7)<<3)];
                #pragma unroll
                for (int mt = 0; mt < 2; ++mt){
                    MFMA_BF16(acc[mt][0], aE[mt][kk], b0);
                    MFMA_BF16(acc[mt][1], aE[mt][kk], b1);
                }
            }
            __builtin_amdgcn_s_setprio(0);
        }

        // ---- GEMM1 epilogue: silu, gate partials, m -> sM ----
        {
            float pg[2] = {0.f, 0.f};
            #pragma unroll
            for (int mt = 0; mt < 2; ++mt){
                const f32x4 iwv = *(const f32x4*)&iw[wm*32 + mt*16 + lg*4];
                #pragma unroll
                for (int nt = 0; nt < 2; ++nt){
                    #pragma unroll
                    for (int i = 0; i < 4; ++i){
                        acc[mt][nt][i] = siluf_(acc[mt][nt][i]);
                        pg[nt] = fmaf(acc[mt][nt][i], iwv[i], pg[nt]);
                    }
                    const int jr = wn*32 + nt*16 + lr;
                    uint2 mv;
                    mv.x = cvtpk_bf16(acc[mt][nt][0], acc[mt][nt][1]);
                    mv.y = cvtpk_bf16(acc[mt][nt][2], acc[mt][nt][3]);
                    *(uint2*)&sM[((jr<<7) + wm*32 + mt*16 + lg*4) ^ ((jr&7)<<3)] = mv;
                }
            }
            pg[0] += __shfl_xor(pg[0], 16); pg[0] += __shfl_xor(pg[0], 32);
            pg[1] += __shfl_xor(pg[1], 16); pg[1] += __shfl_xor(pg[1], 32);
            if (lg == 0){
                gpart[wm][wn*32 + lr]      = pg[0];
                gpart[wm][wn*32 + 16 + lr] = pg[1];
            }
        }
        __syncthreads();   // B: gpart + sM ready

        // ---- gate (per-thread, redundant) + msg accumulation from live m ----
        {
            const int jr0 = wn*32 + lr, jr1 = jr0 + 16;
            const float g0 = sigmoidf_(gpart[0][jr0]+gpart[1][jr0]+gpart[2][jr0]+gpart[3][jr0]);
            const float g1 = sigmoidf_(gpart[0][jr1]+gpart[1][jr1]+gpart[2][jr1]+gpart[3][jr1]);
            #pragma unroll
            for (int mt = 0; mt < 2; ++mt)
                #pragma unroll
                for (int i = 0; i < 4; ++i){
                    msgacc[mt*4+i] = fmaf(acc[mt][0][i], g0, msgacc[mt*4+i]);
                    msgacc[mt*4+i] = fmaf(acc[mt][1][i], g1, msgacc[mt*4+i]);
                }
        }

        // ---- GEMM2: c1 = silu(cw1T @ mT), coord partials ----
        #pragma unroll
        for (int mt = 0; mt < 2; ++mt){
            acc[mt][0] = (f32x4){0.f,0.f,0.f,0.f};
            acc[mt][1] = (f32x4){0.f,0.f,0.f,0.f};
        }
        {
            const int jb0 = wn*32 + lr;
            const int jb1 = jb0 + 16;
            __builtin_amdgcn_s_setprio(1);
            #pragma unroll
            for (int kk = 0; kk < 4; ++kk){
                const int kb = kk*32 + lg*8;
                const bf16x8 b0 = *(const bf16x8*)&sM[((jb0<<7) + kb) ^ ((jb0&7)<<3)];
                const bf16x8 b1 = *(const bf16x8*)&sM[((jb1<<7) + kb) ^ ((jb1&7)<<3)];
                #pragma unroll
                for (int mt = 0; mt < 2; ++mt){
                    MFMA_BF16(acc[mt][0], aC[mt][kk], b0);
                    MFMA_BF16(acc[mt][1], aC[mt][kk], b1);
                }
            }
            __builtin_amdgcn_s_setprio(0);
        }
        {
            float pc[2] = {0.f, 0.f};
            #pragma unroll
            for (int mt = 0; mt < 2; ++mt){
                const f32x4 cwv = *(const f32x4*)&cw2[wm*32 + mt*16 + lg*4];
                #pragma unroll
                for (int nt = 0; nt < 2; ++nt)
                    #pragma unroll
                    for (int i = 0; i < 4; ++i)
                        pc[nt] = fmaf(siluf_(acc[mt][nt][i]), cwv[i], pc[nt]);
            }
            pc[0] += __shfl_xor(pc[0], 16); pc[0] += __shfl_xor(pc[0], 32);
            pc[1] += __shfl_xor(pc[1], 16); pc[1] += __shfl_xor(pc[1], 32);
            if (lg == 0){
                cpart[wm][wn*32 + lr]      = pc[0];
                cpart[wm][wn*32 + 16 + lr] = pc[1];
            }
        }
        __syncthreads();   // C: cpart ready

        // ---- pos accumulation (threads 0..63, one j each) ----
        if (tid < JT){
            const float c = cpart[0][tid] + cpart[1][tid] + cpart[2][tid] + cpart[3][tid];
            const int j = j0 + tid;
            const float pjx = posb[j*3+0], pjy = posb[j*3+1], pjz = posb[j*3+2];
            const float dx = pix-pjx, dy = piy-pjy, dz = piz-pjz;
            const float d2 = dx*dx + dy*dy + dz*dz;
            const float inv = 1.0f / fmaxf(sqrtf(d2), 1e-10f);
            const float cd = c * inv;
            pax = fmaf(dx, cd, pax);
            pay = fmaf(dy, cd, pay);
            paz = fmaf(dz, cd, paz);
        }
        // next-tile sH1 writes are fenced: all sH1 reads ended before B(t);
        // cpart reads end before A(t+1)'s following B; gpart likewise.
    }

    // ---- finalize msg: reduce over lr (j) lanes, combine wn halves via LDS ----
    #pragma unroll
    for (int s = 0; s < 8; ++s){
        msgacc[s] += __shfl_xor(msgacc[s], 1);
        msgacc[s] += __shfl_xor(msgacc[s], 2);
        msgacc[s] += __shfl_xor(msgacc[s], 4);
        msgacc[s] += __shfl_xor(msgacc[s], 8);
    }
    if (lr == 0){
        #pragma unroll
        for (int mt = 0; mt < 2; ++mt)
            #pragma unroll
            for (int i = 0; i < 4; ++i)
                msgp[wn][wm*32 + mt*16 + lg*4 + i] = msgacc[mt*4+i];
    }

    // ---- finalize pos: wave-0 reduce ----
    if (w == 0){
        float sx = pax, sy = pay, sz = paz;
        #pragma unroll
        for (int off = 1; off <= 32; off <<= 1){
            sx += __shfl_xor(sx, off);
            sy += __shfl_xor(sy, off);
            sz += __shfl_xor(sz, off);
        }
        if (l == 0){ red3[0] = sx; red3[1] = sy; red3[2] = sz; }
    }
    __syncthreads();

    const float scale = validi * (1.0f/NN);
    if (tid < HD){
        ni[tid]      = nf[(size_t)bi*HD + tid];
        ni[HD + tid] = (msgp[0][tid] + msgp[1][tid]) * scale;
    }
    if (tid == 0){
        out[(size_t)bi*3+0] = pix + red3[0]*scale;
        out[(size_t)bi*3+1] = piy + red3[1]*scale;
        out[(size_t)bi*3+2] = piz + red3[2]*scale;
    }
    __syncthreads();

    // ---- node MLP (fp32, K split 4 ways over q4) ----
    float p1 = 0.f;
    #pragma unroll 4
    for (int f = 0; f < 64; ++f){
        const int ff = q4*64 + f;
        p1 = fmaf(ni[ff], nw1[ff*HD + hh], p1);
    }
    np4[q4][hh] = p1;
    __syncthreads();
    if (tid < HD) n1l[tid] = siluf_(np4[0][tid]+np4[1][tid]+np4[2][tid]+np4[3][tid]);
    __syncthreads();
    float p2 = 0.f;
    #pragma unroll 4
    for (int k = 0; k < 32; ++k){
        const int kk2 = q4*32 + k;
        p2 = fmaf(n1l[kk2], nw2[kk2*HD + hh], p2);
    }
    np4[q4][hh] = p2;
    __syncthreads();
    if (tid < HD){
        out[(size_t)BB*NN*3 + (size_t)bi*HD + tid] =
            nf[(size_t)bi*HD + tid] + np4[0][tid]+np4[1][tid]+np4[2][tid]+np4[3][tid];
    }
}

extern "C" void kernel_launch(void* const* d_in, const int* in_sizes, int n_in,
                              void* d_out, int out_size, void* d_ws, size_t ws_size,
                              hipStream_t stream)
{
    const float* nf    = (const float*)d_in[0];
    const float* pos   = (const float*)d_in[1];
    const float* valid = (const float*)d_in[2];
    const float* adj   = (const float*)d_in[3];
    const float* ew1   = (const float*)d_in[4];
    const float* ew2   = (const float*)d_in[5];
    const float* cw1   = (const float*)d_in[6];
    const float* cw2   = (const float*)d_in[7];
    const float* nw1   = (const float*)d_in[8];
    const float* nw2   = (const float*)d_in[9];
    const float* iw    = (const float*)d_in[10];
    float* out = (float*)d_out;

    // ws layout: wE(32KB) | wC(32KB) | T0(512KB) | T1(512KB)
    unsigned short* wE  = (unsigned short*)d_ws;
    unsigned short* wC  = wE + 16384;
    unsigned short* T0u = wC + 16384;
    unsigned short* T1u = T0u + (size_t)BB*NN*HD;

    hipLaunchKernelGGL(prep_w, dim3(128), dim3(256), 0, stream, ew2, cw1, wE);
    hipLaunchKernelGGL(precompute_T, dim3(BB*NN), dim3(HD), 0, stream,
                       nf, ew1, T0u, T1u);
    hipLaunchKernelGGL(egcl_main, dim3(BB*NN), dim3(512), 0, stream,
                       nf, pos, valid, adj, ew1, cw2, nw1, nw2, iw,
                       T0u, T1u, wE, wC, out);
}

// Round 8
// 280.956 us; speedup vs baseline: 1.0970x; 1.0970x over previous
//
#include <hip/hip_runtime.h>
#include <hip/hip_bf16.h>

// EGCL, MFMA. B=8, N=256, NF=H=128.
// edge_input@ew1 factorized: T0[i] + T1[j] + dist*ew1[256] + adj*ew1[257].
// Per block (one (b,i)): 256 threads = 4 waves, wave = h-QUARTER (32 h),
// each wave covers ALL 64 j of the tile. j-tiles of 64, 4 iters,
// 3 barriers/tile. Weights 64 VGPR/thread (loaded once), budget 170
// via __launch_bounds__(256,3) -> 3 blocks/CU.
// GEMM1: mT[h][j] = sum_k ew2T[h][k]*h1[j][k]; GEMM2: c1T = cw1T * mT.

#define BB 8
#define NN 256
#define HD 128
#define JT 64
#define NT (NN/JT)

typedef short bf16x8 __attribute__((ext_vector_type(8)));
typedef float f32x4  __attribute__((ext_vector_type(4)));

__device__ __forceinline__ float sigmoidf_(float x){ return 1.0f/(1.0f+__expf(-x)); }
__device__ __forceinline__ float siluf_(float x){ return x/(1.0f+__expf(-x)); }
__device__ __forceinline__ unsigned int cvtpk_bf16(float lo, float hi){
    unsigned int r;
    asm("v_cvt_pk_bf16_f32 %0, %1, %2" : "=v"(r) : "v"(lo), "v"(hi));
    return r;
}
__device__ __forceinline__ unsigned short f2bf(float x){
    unsigned int u = __float_as_uint(x);
    u += 0x7FFF + ((u>>16)&1);
    return (unsigned short)(u>>16);
}
__device__ __forceinline__ float bf2f(unsigned short h){
    return __uint_as_float(((unsigned int)h)<<16);
}

#define MFMA_BF16(d,a,b) d = __builtin_amdgcn_mfma_f32_16x16x32_bf16(a, b, d, 0, 0, 0)

// ---------- prep kernels ----------

__global__ __launch_bounds__(128) void precompute_T(
    const float* __restrict__ nf, const float* __restrict__ ew1,
    unsigned short* __restrict__ T0, unsigned short* __restrict__ T1)
{
    __shared__ float nfs[HD];
    const int bi = blockIdx.x;
    const int h  = threadIdx.x;
    nfs[h] = nf[(size_t)bi*HD + h];
    __syncthreads();
    float a0 = 0.f, a1 = 0.f;
    #pragma unroll 4
    for (int f = 0; f < HD; ++f){
        const float v = nfs[f];
        a0 = fmaf(v, ew1[f*HD + h],      a0);
        a1 = fmaf(v, ew1[(HD+f)*HD + h], a1);
    }
    T0[bi*HD + h] = f2bf(a0);
    T1[bi*HD + h] = f2bf(a1);
}

// plain transposed bf16 weights: dst[m][h*128+k] = src_m[k][h]
__global__ __launch_bounds__(256) void prep_w(
    const float* __restrict__ ew2, const float* __restrict__ cw1,
    unsigned short* __restrict__ dst)
{
    const int e = blockIdx.x*256 + threadIdx.x;   // 0..32767
    const int m = e >> 14;
    const int rem = e & 16383;
    const int h = rem >> 7, k = rem & 127;
    const float* src = m ? cw1 : ew2;
    dst[e] = f2bf(src[k*HD + h]);
}

// ---------- main kernel ----------

__global__ __launch_bounds__(256, 3) void egcl_main(
    const float* __restrict__ nf,  const float* __restrict__ pos,
    const float* __restrict__ valid, const float* __restrict__ adj,
    const float* __restrict__ ew1,
    const float* __restrict__ cw2,
    const float* __restrict__ nw1, const float* __restrict__ nw2,
    const float* __restrict__ iw,
    const unsigned short* __restrict__ T0u, const unsigned short* __restrict__ T1u,
    const unsigned short* __restrict__ wE,  const unsigned short* __restrict__ wC,
    float* __restrict__ out)
{
    __shared__ unsigned short sH1[JT*HD];   // 16KB, [j][k] swizzled
    __shared__ unsigned short sM [JT*HD];   // 16KB, [j][h] swizzled
    __shared__ float gpart[4][JT];
    __shared__ float cpart[4][JT];
    __shared__ float msgp[HD];
    __shared__ float ni[2*HD], n1l[HD], np2[2][HD];
    __shared__ float red3[3];

    const int tid = threadIdx.x;
    const int bi  = blockIdx.x;
    const int b   = bi >> 8;
    const int wm  = tid >> 6;          // wave = h-quarter 0..3 (rows wm*32..wm*32+31)
    const int l   = tid & 63, lr = l & 15, lg = l >> 4;
    const int hp  = tid & 63,  jq = tid >> 6;   // P1 mapping
    const int hh  = tid & 127, half = tid >> 7; // node-MLP mapping

    // ---- load weight A-fragments into registers ONCE (rows h = wm*32+mt*16+lr) ----
    bf16x8 aE[2][4], aC[2][4];
    {
        const unsigned short* pE = wE + (((wm*32 + lr) << 7) + lg*8);
        const unsigned short* pC = wC + (((wm*32 + lr) << 7) + lg*8);
        #pragma unroll
        for (int mt = 0; mt < 2; ++mt)
            #pragma unroll
            for (int kk = 0; kk < 4; ++kk){
                aE[mt][kk] = *(const bf16x8*)(pE + (mt*16 << 7) + kk*32);
                aC[mt][kk] = *(const bf16x8*)(pC + (mt*16 << 7) + kk*32);
            }
    }

    // ---- per-thread P1 constants ----
    const float t0a = bf2f(T0u[bi*HD + 2*hp]);
    const float t0b = bf2f(T0u[bi*HD + 2*hp + 1]);
    const float w6a = ew1[256*HD + 2*hp], w6b = ew1[256*HD + 2*hp + 1];
    const float w7a = ew1[257*HD + 2*hp], w7b = ew1[257*HD + 2*hp + 1];
    const float pix = pos[bi*3+0], piy = pos[bi*3+1], piz = pos[bi*3+2];
    const float validi = valid[bi];
    const unsigned short* __restrict__ T1b = T1u + (size_t)(b*NN)*HD;
    const float* __restrict__ posb   = pos + (size_t)(b*NN)*3;
    const float* __restrict__ adjrow = adj + (size_t)bi*NN;

    float msgacc[8];
    #pragma unroll
    for (int s = 0; s < 8; ++s) msgacc[s] = 0.f;
    float pax = 0.f, pay = 0.f, paz = 0.f;   // tid<64 only

    for (int t = 0; t < NT; ++t){
        const int j0 = t*JT;

        // ---- P1: h1 = silu(first-layer preact) -> sH1 (bf16, swizzled) ----
        #pragma unroll 2
        for (int r = 0; r < 16; ++r){
            const int jl = jq*16 + r;
            const int j  = j0 + jl;
            const ushort2 t1v = *(const ushort2*)&T1b[(size_t)j*HD + 2*hp];
            const float pjx = posb[j*3+0], pjy = posb[j*3+1], pjz = posb[j*3+2];
            const float dx = pix-pjx, dy = piy-pjy, dz = piz-pjz;
            const float d2 = dx*dx + dy*dy + dz*dz;
            const float aj = adjrow[j];
            const float s0 = siluf_(fmaf(aj, w7a, fmaf(d2, w6a, t0a + bf2f(t1v.x))));
            const float s1 = siluf_(fmaf(aj, w7b, fmaf(d2, w6b, t0b + bf2f(t1v.y))));
            ((unsigned int*)sH1)[(jl*64 + hp) ^ ((jl&7)<<2)] = cvtpk_bf16(s0, s1);
        }
        __syncthreads();   // A: h1 ready

        // ---- GEMM1: m = silu(ew2T @ h1T); wave covers 32h x 64j ----
        f32x4 acc[2][4];
        #pragma unroll
        for (int mt = 0; mt < 2; ++mt)
            #pragma unroll
            for (int nt = 0; nt < 4; ++nt)
                acc[mt][nt] = (f32x4){0.f,0.f,0.f,0.f};
        {
            __builtin_amdgcn_s_setprio(1);
            #pragma unroll
            for (int kk = 0; kk < 4; ++kk){
                const int kb = kk*32 + lg*8;
                bf16x8 bf[4];
                #pragma unroll
                for (int nt = 0; nt < 4; ++nt){
                    const int jb = nt*16 + lr;
                    bf[nt] = *(const bf16x8*)&sH1[((jb<<7) + kb) ^ ((jb&7)<<3)];
                }
                #pragma unroll
                for (int mt = 0; mt < 2; ++mt)
                    #pragma unroll
                    for (int nt = 0; nt < 4; ++nt)
                        MFMA_BF16(acc[mt][nt], aE[mt][kk], bf[nt]);
            }
            __builtin_amdgcn_s_setprio(0);
        }

        // ---- GEMM1 epilogue: silu, gate partials, m -> sM ----
        {
            float pg[4] = {0.f,0.f,0.f,0.f};
            #pragma unroll
            for (int mt = 0; mt < 2; ++mt){
                const f32x4 iwv = *(const f32x4*)&iw[wm*32 + mt*16 + lg*4];
                #pragma unroll
                for (int nt = 0; nt < 4; ++nt){
                    #pragma unroll
                    for (int i = 0; i < 4; ++i){
                        acc[mt][nt][i] = siluf_(acc[mt][nt][i]);
                        pg[nt] = fmaf(acc[mt][nt][i], iwv[i], pg[nt]);
                    }
                    const int jr = nt*16 + lr;
                    uint2 mv;
                    mv.x = cvtpk_bf16(acc[mt][nt][0], acc[mt][nt][1]);
                    mv.y = cvtpk_bf16(acc[mt][nt][2], acc[mt][nt][3]);
                    *(uint2*)&sM[((jr<<7) + wm*32 + mt*16 + lg*4) ^ ((jr&7)<<3)] = mv;
                }
            }
            #pragma unroll
            for (int nt = 0; nt < 4; ++nt){
                pg[nt] += __shfl_xor(pg[nt], 16);
                pg[nt] += __shfl_xor(pg[nt], 32);
            }
            if (lg == 0){
                #pragma unroll
                for (int nt = 0; nt < 4; ++nt)
                    gpart[wm][nt*16 + lr] = pg[nt];
            }
        }
        __syncthreads();   // B: gpart + sM ready

        // ---- gate (per-thread, redundant) + msg accumulation from live m ----
        #pragma unroll
        for (int nt = 0; nt < 4; ++nt){
            const int jr = nt*16 + lr;
            const float g = sigmoidf_(gpart[0][jr]+gpart[1][jr]+gpart[2][jr]+gpart[3][jr]);
            #pragma unroll
            for (int mt = 0; mt < 2; ++mt)
                #pragma unroll
                for (int i = 0; i < 4; ++i)
                    msgacc[mt*4+i] = fmaf(acc[mt][nt][i], g, msgacc[mt*4+i]);
        }

        // ---- GEMM2: c1 = silu(cw1T @ mT), coord partials ----
        #pragma unroll
        for (int mt = 0; mt < 2; ++mt)
            #pragma unroll
            for (int nt = 0; nt < 4; ++nt)
                acc[mt][nt] = (f32x4){0.f,0.f,0.f,0.f};
        {
            __builtin_amdgcn_s_setprio(1);
            #pragma unroll
            for (int kk = 0; kk < 4; ++kk){
                const int kb = kk*32 + lg*8;
                bf16x8 bf[4];
                #pragma unroll
                for (int nt = 0; nt < 4; ++nt){
                    const int jb = nt*16 + lr;
                    bf[nt] = *(const bf16x8*)&sM[((jb<<7) + kb) ^ ((jb&7)<<3)];
                }
                #pragma unroll
                for (int mt = 0; mt < 2; ++mt)
                    #pragma unroll
                    for (int nt = 0; nt < 4; ++nt)
                        MFMA_BF16(acc[mt][nt], aC[mt][kk], bf[nt]);
            }
            __builtin_amdgcn_s_setprio(0);
        }
        {
            float pc[4] = {0.f,0.f,0.f,0.f};
            #pragma unroll
            for (int mt = 0; mt < 2; ++mt){
                const f32x4 cwv = *(const f32x4*)&cw2[wm*32 + mt*16 + lg*4];
                #pragma unroll
                for (int nt = 0; nt < 4; ++nt)
                    #pragma unroll
                    for (int i = 0; i < 4; ++i)
                        pc[nt] = fmaf(siluf_(acc[mt][nt][i]), cwv[i], pc[nt]);
            }
            #pragma unroll
            for (int nt = 0; nt < 4; ++nt){
                pc[nt] += __shfl_xor(pc[nt], 16);
                pc[nt] += __shfl_xor(pc[nt], 32);
            }
            if (lg == 0){
                #pragma unroll
                for (int nt = 0; nt < 4; ++nt)
                    cpart[wm][nt*16 + lr] = pc[nt];
            }
        }
        __syncthreads();   // C: cpart ready

        // ---- pos accumulation (threads 0..63, one j each) ----
        if (tid < JT){
            const float c = cpart[0][tid] + cpart[1][tid] + cpart[2][tid] + cpart[3][tid];
            const int j = j0 + tid;
            const float pjx = posb[j*3+0], pjy = posb[j*3+1], pjz = posb[j*3+2];
            const float dx = pix-pjx, dy = piy-pjy, dz = piz-pjz;
            const float d2 = dx*dx + dy*dy + dz*dz;
            const float inv = 1.0f / fmaxf(sqrtf(d2), 1e-10f);
            const float cd = c * inv;
            pax = fmaf(dx, cd, pax);
            pay = fmaf(dy, cd, pay);
            paz = fmaf(dz, cd, paz);
        }
        // barrier analysis: sH1 writes(t+1) vs reads(t) fenced by B(t);
        // gpart read(t) vs write(t+1) fenced by C(t)+A(t+1); cpart read(t)
        // vs write(t+1) fenced by A(t+1)+B(t+1); sM reads(t) end before C(t).
    }

    // ---- finalize msg: reduce over lr (j) lanes; each h owned by one wave ----
    #pragma unroll
    for (int s = 0; s < 8; ++s){
        msgacc[s] += __shfl_xor(msgacc[s], 1);
        msgacc[s] += __shfl_xor(msgacc[s], 2);
        msgacc[s] += __shfl_xor(msgacc[s], 4);
        msgacc[s] += __shfl_xor(msgacc[s], 8);
    }
    if (lr == 0){
        #pragma unroll
        for (int mt = 0; mt < 2; ++mt)
            #pragma unroll
            for (int i = 0; i < 4; ++i)
                msgp[wm*32 + mt*16 + lg*4 + i] = msgacc[mt*4+i];
    }

    // ---- finalize pos: wave-0 reduce ----
    if (wm == 0){
        float sx = pax, sy = pay, sz = paz;
        #pragma unroll
        for (int off = 1; off <= 32; off <<= 1){
            sx += __shfl_xor(sx, off);
            sy += __shfl_xor(sy, off);
            sz += __shfl_xor(sz, off);
        }
        if (l == 0){ red3[0] = sx; red3[1] = sy; red3[2] = sz; }
    }
    __syncthreads();

    const float scale = validi * (1.0f/NN);
    if (tid < HD){
        ni[tid]      = nf[(size_t)bi*HD + tid];
        ni[HD + tid] = msgp[tid] * scale;
    }
    if (tid == 0){
        out[(size_t)bi*3+0] = pix + red3[0]*scale;
        out[(size_t)bi*3+1] = piy + red3[1]*scale;
        out[(size_t)bi*3+2] = piz + red3[2]*scale;
    }
    __syncthreads();

    // ---- node MLP (fp32, K split across halves) ----
    float p1 = 0.f;
    for (int f = 0; f < HD; ++f){
        const int ff = half*HD + f;
        p1 = fmaf(ni[ff], nw1[ff*HD + hh], p1);
    }
    np2[half][hh] = p1;
    __syncthreads();
    if (tid < HD) n1l[tid] = siluf_(np2[0][tid] + np2[1][tid]);
    __syncthreads();
    float p2 = 0.f;
    for (int k = 0; k < 64; ++k){
        const int kk2 = half*64 + k;
        p2 = fmaf(n1l[kk2], nw2[kk2*HD + hh], p2);
    }
    np2[half][hh] = p2;
    __syncthreads();
    if (tid < HD){
        out[(size_t)BB*NN*3 + (size_t)bi*HD + tid] =
            nf[(size_t)bi*HD + tid] + np2[0][tid] + np2[1][tid];
    }
}

extern "C" void kernel_launch(void* const* d_in, const int* in_sizes, int n_in,
                              void* d_out, int out_size, void* d_ws, size_t ws_size,
                              hipStream_t stream)
{
    const float* nf    = (const float*)d_in[0];
    const float* pos   = (const float*)d_in[1];
    const float* valid = (const float*)d_in[2];
    const float* adj   = (const float*)d_in[3];
    const float* ew1   = (const float*)d_in[4];
    const float* ew2   = (const float*)d_in[5];
    const float* cw1   = (const float*)d_in[6];
    const float* cw2   = (const float*)d_in[7];
    const float* nw1   = (const float*)d_in[8];
    const float* nw2   = (const float*)d_in[9];
    const float* iw    = (const float*)d_in[10];
    float* out = (float*)d_out;

    // ws layout: wE(32KB) | wC(32KB) | T0(512KB) | T1(512KB)
    unsigned short* wE  = (unsigned short*)d_ws;
    unsigned short* wC  = wE + 16384;
    unsigned short* T0u = wC + 16384;
    unsigned short* T1u = T0u + (size_t)BB*NN*HD;

    hipLaunchKernelGGL(prep_w, dim3(128), dim3(256), 0, stream, ew2, cw1, wE);
    hipLaunchKernelGGL(precompute_T, dim3(BB*NN), dim3(HD), 0, stream,
                       nf, ew1, T0u, T1u);
    hipLaunchKernelGGL(egcl_main, dim3(BB*NN), dim3(256), 0, stream,
                       nf, pos, valid, adj, ew1, cw2, nw1, nw2, iw,
                       T0u, T1u, wE, wC, out);
}

// Round 9
// 196.738 us; speedup vs baseline: 1.5667x; 1.4281x over previous
//
#include <hip/hip_runtime.h>
#include <hip/hip_bf16.h>

// EGCL, MFMA, mixed weight storage. B=8, N=256, NF=H=128.
// edge_input@ew1 factorized: T0[i] + T1[j] + dist*ew1[256] + adj*ew1[257].
// Per block (one (b,i)): 256 threads = 4 waves, wave = h-QUARTER (32 h),
// covers all 64 j. j-tiles of 64, 4 iters, 4 barriers/tile.
// GEMM1: A = ew2T in VGPRs (32 regs, loaded once); B = h1 from LDS.
// GEMM2: A = cw1T from LDS (32KB, staged ONCE per block); B = m from LDS.
// h1 and m share ONE 16KB LDS buffer (barrier between read/overwrite).
// Node-MLP scratch aliases the cw1T LDS region after the main loop.

#define BB 8
#define NN 256
#define HD 128
#define JT 64
#define NT (NN/JT)

typedef short bf16x8 __attribute__((ext_vector_type(8)));
typedef float f32x4  __attribute__((ext_vector_type(4)));

__device__ __forceinline__ float sigmoidf_(float x){ return 1.0f/(1.0f+__expf(-x)); }
__device__ __forceinline__ float siluf_(float x){ return x/(1.0f+__expf(-x)); }
__device__ __forceinline__ unsigned int cvtpk_bf16(float lo, float hi){
    unsigned int r;
    asm("v_cvt_pk_bf16_f32 %0, %1, %2" : "=v"(r) : "v"(lo), "v"(hi));
    return r;
}
__device__ __forceinline__ unsigned short f2bf(float x){
    unsigned int u = __float_as_uint(x);
    u += 0x7FFF + ((u>>16)&1);
    return (unsigned short)(u>>16);
}
__device__ __forceinline__ float bf2f(unsigned short h){
    return __uint_as_float(((unsigned int)h)<<16);
}

#define MFMA_BF16(d,a,b) d = __builtin_amdgcn_mfma_f32_16x16x32_bf16(a, b, d, 0, 0, 0)

// ---------- prep kernels ----------

__global__ __launch_bounds__(128) void precompute_T(
    const float* __restrict__ nf, const float* __restrict__ ew1,
    unsigned short* __restrict__ T0, unsigned short* __restrict__ T1)
{
    __shared__ float nfs[HD];
    const int bi = blockIdx.x;
    const int h  = threadIdx.x;
    nfs[h] = nf[(size_t)bi*HD + h];
    __syncthreads();
    float a0 = 0.f, a1 = 0.f;
    #pragma unroll 4
    for (int f = 0; f < HD; ++f){
        const float v = nfs[f];
        a0 = fmaf(v, ew1[f*HD + h],      a0);
        a1 = fmaf(v, ew1[(HD+f)*HD + h], a1);
    }
    T0[bi*HD + h] = f2bf(a0);
    T1[bi*HD + h] = f2bf(a1);
}

// wE: plain transposed bf16 ew2T [h][k] (consumed into registers).
// wC: transposed + XOR-swizzled cw1T (consumed by linear LDS copy + swizzled ds_read).
__global__ __launch_bounds__(256) void prep_w(
    const float* __restrict__ ew2, const float* __restrict__ cw1,
    unsigned short* __restrict__ dst)
{
    const int e = blockIdx.x*256 + threadIdx.x;   // 0..32767
    const int m = e >> 14;
    const int rem = e & 16383;
    const int h = rem >> 7, k = rem & 127;
    if (m == 0)
        dst[rem] = f2bf(ew2[k*HD + h]);                                  // plain
    else
        dst[16384 + ((((h<<7) | k) ^ ((h&7)<<3)))] = f2bf(cw1[k*HD + h]); // swizzled
}

// ---------- main kernel ----------

__global__ __launch_bounds__(256) void egcl_main(
    const float* __restrict__ nf,  const float* __restrict__ pos,
    const float* __restrict__ valid, const float* __restrict__ adj,
    const float* __restrict__ ew1,
    const float* __restrict__ cw2,
    const float* __restrict__ nw1, const float* __restrict__ nw2,
    const float* __restrict__ iw,
    const unsigned short* __restrict__ T0u, const unsigned short* __restrict__ T1u,
    const unsigned short* __restrict__ wE,  const unsigned short* __restrict__ wC,
    float* __restrict__ out)
{
    __shared__ unsigned short sW [16384];   // 32KB cw1T [h'][k] swizzled (staged once)
    __shared__ unsigned short sHM[JT*HD];   // 16KB shared: h1 [j][k] then m [j][h]
    __shared__ float gpart[4][JT];
    __shared__ float cpart[4][JT];
    __shared__ float msgp[HD];
    __shared__ float red3[3];

    const int tid = threadIdx.x;
    const int bi  = blockIdx.x;
    const int b   = bi >> 8;
    const int wm  = tid >> 6;          // wave = h-quarter 0..3
    const int l   = tid & 63, lr = l & 15, lg = l >> 4;
    const int hp  = tid & 63,  jq = tid >> 6;   // P1 mapping: 16 j per thread
    const int hh  = tid & 127, half = tid >> 7; // node-MLP mapping

    // ---- stage cw1T into LDS ONCE (linear copy; data pre-swizzled) ----
    {
        const uint4* g = (const uint4*)wC;
        uint4* s = (uint4*)sW;
        #pragma unroll
        for (int r = 0; r < 8; ++r) s[r*256 + tid] = g[r*256 + tid];
    }

    // ---- ew2T A-fragments into registers ONCE (rows h = wm*32+mt*16+lr) ----
    bf16x8 aE[2][4];
    {
        const unsigned short* pE = wE + (((wm*32 + lr) << 7) + lg*8);
        #pragma unroll
        for (int mt = 0; mt < 2; ++mt)
            #pragma unroll
            for (int kk = 0; kk < 4; ++kk)
                aE[mt][kk] = *(const bf16x8*)(pE + (mt*16 << 7) + kk*32);
    }

    // ---- per-thread P1 constants ----
    const float t0a = bf2f(T0u[bi*HD + 2*hp]);
    const float t0b = bf2f(T0u[bi*HD + 2*hp + 1]);
    const float w6a = ew1[256*HD + 2*hp], w6b = ew1[256*HD + 2*hp + 1];
    const float w7a = ew1[257*HD + 2*hp], w7b = ew1[257*HD + 2*hp + 1];
    const float pix = pos[bi*3+0], piy = pos[bi*3+1], piz = pos[bi*3+2];
    const float validi = valid[bi];
    const unsigned short* __restrict__ T1b = T1u + (size_t)(b*NN)*HD;
    const float* __restrict__ posb   = pos + (size_t)(b*NN)*3;
    const float* __restrict__ adjrow = adj + (size_t)bi*NN;

    float msgacc[8];
    #pragma unroll
    for (int s = 0; s < 8; ++s) msgacc[s] = 0.f;
    float pax = 0.f, pay = 0.f, paz = 0.f;   // tid<64 only

    for (int t = 0; t < NT; ++t){
        const int j0 = t*JT;

        // ---- P1: h1 = silu(first-layer preact) -> sHM (bf16, swizzled) ----
        #pragma unroll 2
        for (int r = 0; r < 16; ++r){
            const int jl = jq*16 + r;
            const int j  = j0 + jl;
            const ushort2 t1v = *(const ushort2*)&T1b[(size_t)j*HD + 2*hp];
            const float pjx = posb[j*3+0], pjy = posb[j*3+1], pjz = posb[j*3+2];
            const float dx = pix-pjx, dy = piy-pjy, dz = piz-pjz;
            const float d2 = dx*dx + dy*dy + dz*dz;
            const float aj = adjrow[j];
            const float s0 = siluf_(fmaf(aj, w7a, fmaf(d2, w6a, t0a + bf2f(t1v.x))));
            const float s1 = siluf_(fmaf(aj, w7b, fmaf(d2, w6b, t0b + bf2f(t1v.y))));
            ((unsigned int*)sHM)[(jl*64 + hp) ^ ((jl&7)<<2)] = cvtpk_bf16(s0, s1);
        }
        __syncthreads();   // A: h1 ready (also fences sW staging on t=0)

        // ---- GEMM1: m = silu(ew2T @ h1T); A in regs, B from sHM ----
        f32x4 acc[2][4];
        #pragma unroll
        for (int mt = 0; mt < 2; ++mt)
            #pragma unroll
            for (int nt = 0; nt < 4; ++nt)
                acc[mt][nt] = (f32x4){0.f,0.f,0.f,0.f};
        {
            __builtin_amdgcn_s_setprio(1);
            #pragma unroll
            for (int kk = 0; kk < 4; ++kk){
                const int kb = kk*32 + lg*8;
                bf16x8 bf[4];
                #pragma unroll
                for (int nt = 0; nt < 4; ++nt){
                    const int jb = nt*16 + lr;
                    bf[nt] = *(const bf16x8*)&sHM[((jb<<7) + kb) ^ ((jb&7)<<3)];
                }
                #pragma unroll
                for (int mt = 0; mt < 2; ++mt)
                    #pragma unroll
                    for (int nt = 0; nt < 4; ++nt)
                        MFMA_BF16(acc[mt][nt], aE[mt][kk], bf[nt]);
            }
            __builtin_amdgcn_s_setprio(0);
        }
        __syncthreads();   // B: all waves done reading h1 -> sHM reusable

        // ---- GEMM1 epilogue: silu, gate partials, m -> sHM (overwrite) ----
        {
            float pg[4] = {0.f,0.f,0.f,0.f};
            #pragma unroll
            for (int mt = 0; mt < 2; ++mt){
                const f32x4 iwv = *(const f32x4*)&iw[wm*32 + mt*16 + lg*4];
                #pragma unroll
                for (int nt = 0; nt < 4; ++nt){
                    #pragma unroll
                    for (int i = 0; i < 4; ++i){
                        acc[mt][nt][i] = siluf_(acc[mt][nt][i]);
                        pg[nt] = fmaf(acc[mt][nt][i], iwv[i], pg[nt]);
                    }
                    const int jr = nt*16 + lr;
                    uint2 mv;
                    mv.x = cvtpk_bf16(acc[mt][nt][0], acc[mt][nt][1]);
                    mv.y = cvtpk_bf16(acc[mt][nt][2], acc[mt][nt][3]);
                    *(uint2*)&sHM[((jr<<7) + wm*32 + mt*16 + lg*4) ^ ((jr&7)<<3)] = mv;
                }
            }
            #pragma unroll
            for (int nt = 0; nt < 4; ++nt){
                pg[nt] += __shfl_xor(pg[nt], 16);
                pg[nt] += __shfl_xor(pg[nt], 32);
            }
            if (lg == 0){
                #pragma unroll
                for (int nt = 0; nt < 4; ++nt)
                    gpart[wm][nt*16 + lr] = pg[nt];
            }
        }
        __syncthreads();   // C: m + gpart ready

        // ---- gate (per-thread, redundant) + msg accumulation from live m ----
        #pragma unroll
        for (int nt = 0; nt < 4; ++nt){
            const int jr = nt*16 + lr;
            const float g = sigmoidf_(gpart[0][jr]+gpart[1][jr]+gpart[2][jr]+gpart[3][jr]);
            #pragma unroll
            for (int mt = 0; mt < 2; ++mt)
                #pragma unroll
                for (int i = 0; i < 4; ++i)
                    msgacc[mt*4+i] = fmaf(acc[mt][nt][i], g, msgacc[mt*4+i]);
        }

        // ---- GEMM2: c1 = silu(cw1T @ mT); A from sW, B from sHM ----
        #pragma unroll
        for (int mt = 0; mt < 2; ++mt)
            #pragma unroll
            for (int nt = 0; nt < 4; ++nt)
                acc[mt][nt] = (f32x4){0.f,0.f,0.f,0.f};
        {
            __builtin_amdgcn_s_setprio(1);
            #pragma unroll
            for (int kk = 0; kk < 4; ++kk){
                const int kb = kk*32 + lg*8;
                bf16x8 af[2];
                #pragma unroll
                for (int mt = 0; mt < 2; ++mt){
                    const int hr = wm*32 + mt*16 + lr;
                    af[mt] = *(const bf16x8*)&sW[((hr<<7) + kb) ^ ((hr&7)<<3)];
                }
                bf16x8 bf[4];
                #pragma unroll
                for (int nt = 0; nt < 4; ++nt){
                    const int jb = nt*16 + lr;
                    bf[nt] = *(const bf16x8*)&sHM[((jb<<7) + kb) ^ ((jb&7)<<3)];
                }
                #pragma unroll
                for (int mt = 0; mt < 2; ++mt)
                    #pragma unroll
                    for (int nt = 0; nt < 4; ++nt)
                        MFMA_BF16(acc[mt][nt], af[mt], bf[nt]);
            }
            __builtin_amdgcn_s_setprio(0);
        }
        {
            float pc[4] = {0.f,0.f,0.f,0.f};
            #pragma unroll
            for (int mt = 0; mt < 2; ++mt){
                const f32x4 cwv = *(const f32x4*)&cw2[wm*32 + mt*16 + lg*4];
                #pragma unroll
                for (int nt = 0; nt < 4; ++nt)
                    #pragma unroll
                    for (int i = 0; i < 4; ++i)
                        pc[nt] = fmaf(siluf_(acc[mt][nt][i]), cwv[i], pc[nt]);
            }
            #pragma unroll
            for (int nt = 0; nt < 4; ++nt){
                pc[nt] += __shfl_xor(pc[nt], 16);
                pc[nt] += __shfl_xor(pc[nt], 32);
            }
            if (lg == 0){
                #pragma unroll
                for (int nt = 0; nt < 4; ++nt)
                    cpart[wm][nt*16 + lr] = pc[nt];
            }
        }
        __syncthreads();   // D: cpart ready (+ all sHM m-reads done)

        // ---- pos accumulation (threads 0..63, one j each) ----
        if (tid < JT){
            const float c = cpart[0][tid] + cpart[1][tid] + cpart[2][tid] + cpart[3][tid];
            const int j = j0 + tid;
            const float pjx = posb[j*3+0], pjy = posb[j*3+1], pjz = posb[j*3+2];
            const float dx = pix-pjx, dy = piy-pjy, dz = piz-pjz;
            const float d2 = dx*dx + dy*dy + dz*dz;
            const float inv = 1.0f / fmaxf(sqrtf(d2), 1e-10f);
            const float cd = c * inv;
            pax = fmaf(dx, cd, pax);
            pay = fmaf(dy, cd, pay);
            paz = fmaf(dz, cd, paz);
        }
        // barrier analysis: sHM h1-writes(t+1) vs m-reads(t): fenced by D(t);
        // gpart write(t+1) vs read(t): fenced by C..A(t+1)+B(t+1);
        // cpart write(t+1) vs read(t): fenced by A(t+1)..C(t+1); sW read-only.
    }

    // ---- finalize msg: reduce over lr (j) lanes; each h owned by one wave ----
    #pragma unroll
    for (int s = 0; s < 8; ++s){
        msgacc[s] += __shfl_xor(msgacc[s], 1);
        msgacc[s] += __shfl_xor(msgacc[s], 2);
        msgacc[s] += __shfl_xor(msgacc[s], 4);
        msgacc[s] += __shfl_xor(msgacc[s], 8);
    }
    if (lr == 0){
        #pragma unroll
        for (int mt = 0; mt < 2; ++mt)
            #pragma unroll
            for (int i = 0; i < 4; ++i)
                msgp[wm*32 + mt*16 + lg*4 + i] = msgacc[mt*4+i];
    }

    // ---- finalize pos: wave-0 reduce ----
    if (wm == 0){
        float sx = pax, sy = pay, sz = paz;
        #pragma unroll
        for (int off = 1; off <= 32; off <<= 1){
            sx += __shfl_xor(sx, off);
            sy += __shfl_xor(sy, off);
            sz += __shfl_xor(sz, off);
        }
        if (l == 0){ red3[0] = sx; red3[1] = sy; red3[2] = sz; }
    }
    __syncthreads();   // msgp + red3 ready; sW reads all done -> alias below

    // ---- node MLP scratch aliases the sW region (sW no longer needed) ----
    float* nbuf = (float*)sW;           // ni[256] | n1l[128] | np2[2][128]
    float* ni   = nbuf;
    float* n1l  = nbuf + 256;
    float* np2  = nbuf + 384;

    const float scale = validi * (1.0f/NN);
    if (tid < HD){
        ni[tid]      = nf[(size_t)bi*HD + tid];
        ni[HD + tid] = msgp[tid] * scale;
    }
    if (tid == 0){
        out[(size_t)bi*3+0] = pix + red3[0]*scale;
        out[(size_t)bi*3+1] = piy + red3[1]*scale;
        out[(size_t)bi*3+2] = piz + red3[2]*scale;
    }
    __syncthreads();

    // ---- node MLP (fp32, K split across halves) ----
    float p1 = 0.f;
    for (int f = 0; f < HD; ++f){
        const int ff = half*HD + f;
        p1 = fmaf(ni[ff], nw1[ff*HD + hh], p1);
    }
    np2[half*HD + hh] = p1;
    __syncthreads();
    if (tid < HD) n1l[tid] = siluf_(np2[tid] + np2[HD + tid]);
    __syncthreads();
    float p2 = 0.f;
    for (int k = 0; k < 64; ++k){
        const int kk2 = half*64 + k;
        p2 = fmaf(n1l[kk2], nw2[kk2*HD + hh], p2);
    }
    np2[half*HD + hh] = p2;
    __syncthreads();
    if (tid < HD){
        out[(size_t)BB*NN*3 + (size_t)bi*HD + tid] =
            nf[(size_t)bi*HD + tid] + np2[tid] + np2[HD + tid];
    }
}

extern "C" void kernel_launch(void* const* d_in, const int* in_sizes, int n_in,
                              void* d_out, int out_size, void* d_ws, size_t ws_size,
                              hipStream_t stream)
{
    const float* nf    = (const float*)d_in[0];
    const float* pos   = (const float*)d_in[1];
    const float* valid = (const float*)d_in[2];
    const float* adj   = (const float*)d_in[3];
    const float* ew1   = (const float*)d_in[4];
    const float* ew2   = (const float*)d_in[5];
    const float* cw1   = (const float*)d_in[6];
    const float* cw2   = (const float*)d_in[7];
    const float* nw1   = (const float*)d_in[8];
    const float* nw2   = (const float*)d_in[9];
    const float* iw    = (const float*)d_in[10];
    float* out = (float*)d_out;

    // ws layout: wE(32KB) | wC(32KB) | T0(512KB) | T1(512KB)
    unsigned short* wE  = (unsigned short*)d_ws;
    unsigned short* wC  = wE + 16384;
    unsigned short* T0u = wC + 16384;
    unsigned short* T1u = T0u + (size_t)BB*NN*HD;

    hipLaunchKernelGGL(prep_w, dim3(128), dim3(256), 0, stream, ew2, cw1, wE);
    hipLaunchKernelGGL(precompute_T, dim3(BB*NN), dim3(HD), 0, stream,
                       nf, ew1, T0u, T1u);
    hipLaunchKernelGGL(egcl_main, dim3(BB*NN), dim3(256), 0, stream,
                       nf, pos, valid, adj, ew1, cw2, nw1, nw2, iw,
                       T0u, T1u, wE, wC, out);
}

// Round 10
// 157.227 us; speedup vs baseline: 1.9604x; 1.2513x over previous
//
#include <hip/hip_runtime.h>
#include <hip/hip_bf16.h>

// EGCL, MFMA, mixed weight storage + rcp-based activations. B=8, N=256, NF=H=128.
// edge_input@ew1 factorized: T0[i] + T1[j] + dist*ew1[256] + adj*ew1[257].
// Per block (one (b,i)): 256 threads = 4 waves, wave = h-QUARTER (32 h),
// covers all 64 j. j-tiles of 64, 4 iters, 4 barriers/tile.
// GEMM1: A = ew2T in VGPRs (32 regs); B = h1 from LDS.
// GEMM2: A = cw1T from LDS (32KB, staged ONCE); B = m from LDS.
// h1/m share one 16KB LDS buffer. silu/sigmoid via v_rcp_f32 (no IEEE div).

#define BB 8
#define NN 256
#define HD 128
#define JT 64
#define NT (NN/JT)

typedef short bf16x8 __attribute__((ext_vector_type(8)));
typedef float f32x4  __attribute__((ext_vector_type(4)));

__device__ __forceinline__ float sigmoidf_(float x){
    return __builtin_amdgcn_rcpf(1.0f + __expf(-x));
}
__device__ __forceinline__ float siluf_(float x){
    return x * __builtin_amdgcn_rcpf(1.0f + __expf(-x));
}
__device__ __forceinline__ unsigned int cvtpk_bf16(float lo, float hi){
    unsigned int r;
    asm("v_cvt_pk_bf16_f32 %0, %1, %2" : "=v"(r) : "v"(lo), "v"(hi));
    return r;
}
__device__ __forceinline__ unsigned short f2bf(float x){
    unsigned int u = __float_as_uint(x);
    u += 0x7FFF + ((u>>16)&1);
    return (unsigned short)(u>>16);
}
__device__ __forceinline__ float bf2f(unsigned short h){
    return __uint_as_float(((unsigned int)h)<<16);
}

#define MFMA_BF16(d,a,b) d = __builtin_amdgcn_mfma_f32_16x16x32_bf16(a, b, d, 0, 0, 0)

// ---------- prep kernels ----------

__global__ __launch_bounds__(128) void precompute_T(
    const float* __restrict__ nf, const float* __restrict__ ew1,
    unsigned short* __restrict__ T0, unsigned short* __restrict__ T1)
{
    __shared__ float nfs[HD];
    const int bi = blockIdx.x;
    const int h  = threadIdx.x;
    nfs[h] = nf[(size_t)bi*HD + h];
    __syncthreads();
    float a0 = 0.f, a1 = 0.f;
    #pragma unroll 4
    for (int f = 0; f < HD; ++f){
        const float v = nfs[f];
        a0 = fmaf(v, ew1[f*HD + h],      a0);
        a1 = fmaf(v, ew1[(HD+f)*HD + h], a1);
    }
    T0[bi*HD + h] = f2bf(a0);
    T1[bi*HD + h] = f2bf(a1);
}

// wE: plain transposed bf16 ew2T [h][k] (consumed into registers).
// wC: transposed + XOR-swizzled cw1T (consumed by linear LDS copy + swizzled ds_read).
__global__ __launch_bounds__(256) void prep_w(
    const float* __restrict__ ew2, const float* __restrict__ cw1,
    unsigned short* __restrict__ dst)
{
    const int e = blockIdx.x*256 + threadIdx.x;   // 0..32767
    const int m = e >> 14;
    const int rem = e & 16383;
    const int h = rem >> 7, k = rem & 127;
    if (m == 0)
        dst[rem] = f2bf(ew2[k*HD + h]);                                  // plain
    else
        dst[16384 + ((((h<<7) | k) ^ ((h&7)<<3)))] = f2bf(cw1[k*HD + h]); // swizzled
}

// ---------- main kernel ----------

__global__ __launch_bounds__(256) void egcl_main(
    const float* __restrict__ nf,  const float* __restrict__ pos,
    const float* __restrict__ valid, const float* __restrict__ adj,
    const float* __restrict__ ew1,
    const float* __restrict__ cw2,
    const float* __restrict__ nw1, const float* __restrict__ nw2,
    const float* __restrict__ iw,
    const unsigned short* __restrict__ T0u, const unsigned short* __restrict__ T1u,
    const unsigned short* __restrict__ wE,  const unsigned short* __restrict__ wC,
    float* __restrict__ out)
{
    __shared__ unsigned short sW [16384];   // 32KB cw1T [h'][k] swizzled (staged once)
    __shared__ unsigned short sHM[JT*HD];   // 16KB shared: h1 [j][k] then m [j][h]
    __shared__ float gpart[4][JT];
    __shared__ float cpart[4][JT];
    __shared__ float msgp[HD];
    __shared__ float red3[3];

    const int tid = threadIdx.x;
    const int bi  = blockIdx.x;
    const int b   = bi >> 8;
    const int wm  = tid >> 6;          // wave = h-quarter 0..3
    const int l   = tid & 63, lr = l & 15, lg = l >> 4;
    const int hp  = tid & 63,  jq = tid >> 6;   // P1 mapping: 16 j per thread
    const int hh  = tid & 127, half = tid >> 7; // node-MLP mapping

    // ---- stage cw1T into LDS ONCE (linear copy; data pre-swizzled) ----
    {
        const uint4* g = (const uint4*)wC;
        uint4* s = (uint4*)sW;
        #pragma unroll
        for (int r = 0; r < 8; ++r) s[r*256 + tid] = g[r*256 + tid];
    }

    // ---- ew2T A-fragments into registers ONCE (rows h = wm*32+mt*16+lr) ----
    bf16x8 aE[2][4];
    {
        const unsigned short* pE = wE + (((wm*32 + lr) << 7) + lg*8);
        #pragma unroll
        for (int mt = 0; mt < 2; ++mt)
            #pragma unroll
            for (int kk = 0; kk < 4; ++kk)
                aE[mt][kk] = *(const bf16x8*)(pE + (mt*16 << 7) + kk*32);
    }

    // ---- per-thread P1 constants ----
    const float t0a = bf2f(T0u[bi*HD + 2*hp]);
    const float t0b = bf2f(T0u[bi*HD + 2*hp + 1]);
    const float w6a = ew1[256*HD + 2*hp], w6b = ew1[256*HD + 2*hp + 1];
    const float w7a = ew1[257*HD + 2*hp], w7b = ew1[257*HD + 2*hp + 1];
    const float pix = pos[bi*3+0], piy = pos[bi*3+1], piz = pos[bi*3+2];
    const float validi = valid[bi];
    const unsigned short* __restrict__ T1b = T1u + (size_t)(b*NN)*HD;
    const float* __restrict__ posb   = pos + (size_t)(b*NN)*3;
    const float* __restrict__ adjrow = adj + (size_t)bi*NN;

    float msgacc[8];
    #pragma unroll
    for (int s = 0; s < 8; ++s) msgacc[s] = 0.f;
    float pax = 0.f, pay = 0.f, paz = 0.f;   // tid<64 only

    for (int t = 0; t < NT; ++t){
        const int j0 = t*JT;

        // ---- P1: h1 = silu(first-layer preact) -> sHM (bf16, swizzled) ----
        #pragma unroll 2
        for (int r = 0; r < 16; ++r){
            const int jl = jq*16 + r;
            const int j  = j0 + jl;
            const ushort2 t1v = *(const ushort2*)&T1b[(size_t)j*HD + 2*hp];
            const float pjx = posb[j*3+0], pjy = posb[j*3+1], pjz = posb[j*3+2];
            const float dx = pix-pjx, dy = piy-pjy, dz = piz-pjz;
            const float d2 = dx*dx + dy*dy + dz*dz;
            const float aj = adjrow[j];
            const float s0 = siluf_(fmaf(aj, w7a, fmaf(d2, w6a, t0a + bf2f(t1v.x))));
            const float s1 = siluf_(fmaf(aj, w7b, fmaf(d2, w6b, t0b + bf2f(t1v.y))));
            ((unsigned int*)sHM)[(jl*64 + hp) ^ ((jl&7)<<2)] = cvtpk_bf16(s0, s1);
        }
        __syncthreads();   // A: h1 ready (also fences sW staging on t=0)

        // ---- GEMM1: m = silu(ew2T @ h1T); A in regs, B from sHM ----
        f32x4 acc[2][4];
        #pragma unroll
        for (int mt = 0; mt < 2; ++mt)
            #pragma unroll
            for (int nt = 0; nt < 4; ++nt)
                acc[mt][nt] = (f32x4){0.f,0.f,0.f,0.f};
        {
            __builtin_amdgcn_s_setprio(1);
            #pragma unroll
            for (int kk = 0; kk < 4; ++kk){
                const int kb = kk*32 + lg*8;
                bf16x8 bf[4];
                #pragma unroll
                for (int nt = 0; nt < 4; ++nt){
                    const int jb = nt*16 + lr;
                    bf[nt] = *(const bf16x8*)&sHM[((jb<<7) + kb) ^ ((jb&7)<<3)];
                }
                #pragma unroll
                for (int mt = 0; mt < 2; ++mt)
                    #pragma unroll
                    for (int nt = 0; nt < 4; ++nt)
                        MFMA_BF16(acc[mt][nt], aE[mt][kk], bf[nt]);
            }
            __builtin_amdgcn_s_setprio(0);
        }
        __syncthreads();   // B: all waves done reading h1 -> sHM reusable

        // ---- GEMM1 epilogue: silu, gate partials, m -> sHM (overwrite) ----
        {
            float pg[4] = {0.f,0.f,0.f,0.f};
            #pragma unroll
            for (int mt = 0; mt < 2; ++mt){
                const f32x4 iwv = *(const f32x4*)&iw[wm*32 + mt*16 + lg*4];
                #pragma unroll
                for (int nt = 0; nt < 4; ++nt){
                    #pragma unroll
                    for (int i = 0; i < 4; ++i){
                        acc[mt][nt][i] = siluf_(acc[mt][nt][i]);
                        pg[nt] = fmaf(acc[mt][nt][i], iwv[i], pg[nt]);
                    }
                    const int jr = nt*16 + lr;
                    uint2 mv;
                    mv.x = cvtpk_bf16(acc[mt][nt][0], acc[mt][nt][1]);
                    mv.y = cvtpk_bf16(acc[mt][nt][2], acc[mt][nt][3]);
                    *(uint2*)&sHM[((jr<<7) + wm*32 + mt*16 + lg*4) ^ ((jr&7)<<3)] = mv;
                }
            }
            #pragma unroll
            for (int nt = 0; nt < 4; ++nt){
                pg[nt] += __shfl_xor(pg[nt], 16);
                pg[nt] += __shfl_xor(pg[nt], 32);
            }
            if (lg == 0){
                #pragma unroll
                for (int nt = 0; nt < 4; ++nt)
                    gpart[wm][nt*16 + lr] = pg[nt];
            }
        }
        __syncthreads();   // C: m + gpart ready

        // ---- gate (per-thread, redundant) + msg accumulation from live m ----
        #pragma unroll
        for (int nt = 0; nt < 4; ++nt){
            const int jr = nt*16 + lr;
            const float g = sigmoidf_(gpart[0][jr]+gpart[1][jr]+gpart[2][jr]+gpart[3][jr]);
            #pragma unroll
            for (int mt = 0; mt < 2; ++mt)
                #pragma unroll
                for (int i = 0; i < 4; ++i)
                    msgacc[mt*4+i] = fmaf(acc[mt][nt][i], g, msgacc[mt*4+i]);
        }

        // ---- GEMM2: c1 = silu(cw1T @ mT); A from sW, B from sHM ----
        #pragma unroll
        for (int mt = 0; mt < 2; ++mt)
            #pragma unroll
            for (int nt = 0; nt < 4; ++nt)
                acc[mt][nt] = (f32x4){0.f,0.f,0.f,0.f};
        {
            __builtin_amdgcn_s_setprio(1);
            #pragma unroll
            for (int kk = 0; kk < 4; ++kk){
                const int kb = kk*32 + lg*8;
                bf16x8 af[2];
                #pragma unroll
                for (int mt = 0; mt < 2; ++mt){
                    const int hr = wm*32 + mt*16 + lr;
                    af[mt] = *(const bf16x8*)&sW[((hr<<7) + kb) ^ ((hr&7)<<3)];
                }
                bf16x8 bf[4];
                #pragma unroll
                for (int nt = 0; nt < 4; ++nt){
                    const int jb = nt*16 + lr;
                    bf[nt] = *(const bf16x8*)&sHM[((jb<<7) + kb) ^ ((jb&7)<<3)];
                }
                #pragma unroll
                for (int mt = 0; mt < 2; ++mt)
                    #pragma unroll
                    for (int nt = 0; nt < 4; ++nt)
                        MFMA_BF16(acc[mt][nt], af[mt], bf[nt]);
            }
            __builtin_amdgcn_s_setprio(0);
        }
        {
            float pc[4] = {0.f,0.f,0.f,0.f};
            #pragma unroll
            for (int mt = 0; mt < 2; ++mt){
                const f32x4 cwv = *(const f32x4*)&cw2[wm*32 + mt*16 + lg*4];
                #pragma unroll
                for (int nt = 0; nt < 4; ++nt)
                    #pragma unroll
                    for (int i = 0; i < 4; ++i)
                        pc[nt] = fmaf(siluf_(acc[mt][nt][i]), cwv[i], pc[nt]);
            }
            #pragma unroll
            for (int nt = 0; nt < 4; ++nt){
                pc[nt] += __shfl_xor(pc[nt], 16);
                pc[nt] += __shfl_xor(pc[nt], 32);
            }
            if (lg == 0){
                #pragma unroll
                for (int nt = 0; nt < 4; ++nt)
                    cpart[wm][nt*16 + lr] = pc[nt];
            }
        }
        __syncthreads();   // D: cpart ready (+ all sHM m-reads done)

        // ---- pos accumulation (threads 0..63, one j each) ----
        if (tid < JT){
            const float c = cpart[0][tid] + cpart[1][tid] + cpart[2][tid] + cpart[3][tid];
            const int j = j0 + tid;
            const float pjx = posb[j*3+0], pjy = posb[j*3+1], pjz = posb[j*3+2];
            const float dx = pix-pjx, dy = piy-pjy, dz = piz-pjz;
            const float d2 = dx*dx + dy*dy + dz*dz;
            const float nrm = __builtin_amdgcn_sqrtf(d2);
            const float inv = __builtin_amdgcn_rcpf(fmaxf(nrm, 1e-10f));
            const float cd = c * inv;
            pax = fmaf(dx, cd, pax);
            pay = fmaf(dy, cd, pay);
            paz = fmaf(dz, cd, paz);
        }
        // barrier analysis: sHM h1-writes(t+1) vs m-reads(t): fenced by D(t);
        // gpart write(t+1) vs read(t): fenced by C..A(t+1)+B(t+1);
        // cpart write(t+1) vs read(t): fenced by A(t+1)..C(t+1); sW read-only.
    }

    // ---- finalize msg: reduce over lr (j) lanes; each h owned by one wave ----
    #pragma unroll
    for (int s = 0; s < 8; ++s){
        msgacc[s] += __shfl_xor(msgacc[s], 1);
        msgacc[s] += __shfl_xor(msgacc[s], 2);
        msgacc[s] += __shfl_xor(msgacc[s], 4);
        msgacc[s] += __shfl_xor(msgacc[s], 8);
    }
    if (lr == 0){
        #pragma unroll
        for (int mt = 0; mt < 2; ++mt)
            #pragma unroll
            for (int i = 0; i < 4; ++i)
                msgp[wm*32 + mt*16 + lg*4 + i] = msgacc[mt*4+i];
    }

    // ---- finalize pos: wave-0 reduce ----
    if (wm == 0){
        float sx = pax, sy = pay, sz = paz;
        #pragma unroll
        for (int off = 1; off <= 32; off <<= 1){
            sx += __shfl_xor(sx, off);
            sy += __shfl_xor(sy, off);
            sz += __shfl_xor(sz, off);
        }
        if (l == 0){ red3[0] = sx; red3[1] = sy; red3[2] = sz; }
    }
    __syncthreads();   // msgp + red3 ready; sW reads all done -> alias below

    // ---- node MLP scratch aliases the sW region (sW no longer needed) ----
    float* nbuf = (float*)sW;           // ni[256] | n1l[128] | np2[2][128]
    float* ni   = nbuf;
    float* n1l  = nbuf + 256;
    float* np2  = nbuf + 384;

    const float scale = validi * (1.0f/NN);
    if (tid < HD){
        ni[tid]      = nf[(size_t)bi*HD + tid];
        ni[HD + tid] = msgp[tid] * scale;
    }
    if (tid == 0){
        out[(size_t)bi*3+0] = pix + red3[0]*scale;
        out[(size_t)bi*3+1] = piy + red3[1]*scale;
        out[(size_t)bi*3+2] = piz + red3[2]*scale;
    }
    __syncthreads();

    // ---- node MLP (fp32, K split across halves) ----
    float p1 = 0.f;
    for (int f = 0; f < HD; ++f){
        const int ff = half*HD + f;
        p1 = fmaf(ni[ff], nw1[ff*HD + hh], p1);
    }
    np2[half*HD + hh] = p1;
    __syncthreads();
    if (tid < HD) n1l[tid] = siluf_(np2[tid] + np2[HD + tid]);
    __syncthreads();
    float p2 = 0.f;
    for (int k = 0; k < 64; ++k){
        const int kk2 = half*64 + k;
        p2 = fmaf(n1l[kk2], nw2[kk2*HD + hh], p2);
    }
    np2[half*HD + hh] = p2;
    __syncthreads();
    if (tid < HD){
        out[(size_t)BB*NN*3 + (size_t)bi*HD + tid] =
            nf[(size_t)bi*HD + tid] + np2[tid] + np2[HD + tid];
    }
}

extern "C" void kernel_launch(void* const* d_in, const int* in_sizes, int n_in,
                              void* d_out, int out_size, void* d_ws, size_t ws_size,
                              hipStream_t stream)
{
    const float* nf    = (const float*)d_in[0];
    const float* pos   = (const float*)d_in[1];
    const float* valid = (const float*)d_in[2];
    const float* adj   = (const float*)d_in[3];
    const float* ew1   = (const float*)d_in[4];
    const float* ew2   = (const float*)d_in[5];
    const float* cw1   = (const float*)d_in[6];
    const float* cw2   = (const float*)d_in[7];
    const float* nw1   = (const float*)d_in[8];
    const float* nw2   = (const float*)d_in[9];
    const float* iw    = (const float*)d_in[10];
    float* out = (float*)d_out;

    // ws layout: wE(32KB) | wC(32KB) | T0(512KB) | T1(512KB)
    unsigned short* wE  = (unsigned short*)d_ws;
    unsigned short* wC  = wE + 16384;
    unsigned short* T0u = wC + 16384;
    unsigned short* T1u = T0u + (size_t)BB*NN*HD;

    hipLaunchKernelGGL(prep_w, dim3(128), dim3(256), 0, stream, ew2, cw1, wE);
    hipLaunchKernelGGL(precompute_T, dim3(BB*NN), dim3(HD), 0, stream,
                       nf, ew1, T0u, T1u);
    hipLaunchKernelGGL(egcl_main, dim3(BB*NN), dim3(256), 0, stream,
                       nf, pos, valid, adj, ew1, cw2, nw1, nw2, iw,
                       T0u, T1u, wE, wC, out);
}